// Round 8
// baseline (222.735 us; speedup 1.0000x reference)
//
#include <hip/hip_runtime.h>
#include <stdint.h>

// N=4096, B=32, LATENT=16, UNITS=64, NNZ=65536, K=2, M=5.
#define NN    4096
#define BB    32
#define NNZE  65536
#define WA    512      // pass-A diffusion width (16*B), row layout [b*16+f]
#define WB    2048     // c width (b*64+u), bf16
#define WD    512      // pass-B diffusion width (16*B), row layout [b*16+u']

typedef __attribute__((ext_vector_type(8))) short bf16x8;
typedef __attribute__((ext_vector_type(4))) float f32x4;

// ---------- bf16 helpers ----------
__device__ __forceinline__ float bf2f_lo(unsigned int u) {
    union { unsigned int x; float f; } c; c.x = u << 16; return c.f;
}
__device__ __forceinline__ float bf2f_hi(unsigned int u) {
    union { unsigned int x; float f; } c; c.x = u & 0xffff0000u; return c.f;
}
__device__ __forceinline__ float bf2f(unsigned int h) {
    union { unsigned int u; float f; } c; c.u = h << 16; return c.f;
}
__device__ __forceinline__ unsigned int f2bf(float f) {
    union { float ff; unsigned int u; } c; c.ff = f;
    return (c.u + 0x7fffu + ((c.u >> 16) & 1u)) >> 16;
}

// ---------- CSR build (both supports per launch) ----------
__global__ void hist2_kernel(const int* __restrict__ r1, const int* __restrict__ r2,
                             int* __restrict__ cnt1, int* __restrict__ cnt2) {
    int e = blockIdx.x * blockDim.x + threadIdx.x;   // < 2*NNZE
    if (e < NNZE) atomicAdd(&cnt1[r1[e]], 1);
    else          atomicAdd(&cnt2[r2[e - NNZE]], 1);
}

__global__ void scan2_kernel(int* cur1, int* rp1, int* cur2, int* rp2) {
    int* cur = (blockIdx.x == 0) ? cur1 : cur2;
    int* rp  = (blockIdx.x == 0) ? rp1  : rp2;
    __shared__ int part[256];
    int t = threadIdx.x;
    int base = t * 16;
    int loc[16];
    int s = 0;
#pragma unroll
    for (int i = 0; i < 16; ++i) { loc[i] = s; s += cur[base + i]; }
    part[t] = s;
    __syncthreads();
    for (int off = 1; off < 256; off <<= 1) {
        int v = 0;
        if (t >= off) v = part[t - off];
        __syncthreads();
        part[t] += v;
        __syncthreads();
    }
    int excl = (t == 0) ? 0 : part[t - 1];
#pragma unroll
    for (int i = 0; i < 16; ++i) rp[base + i] = excl + loc[i];
    __syncthreads();
#pragma unroll
    for (int i = 0; i < 16; ++i) cur[base + i] = rp[base + i];
    if (t == 255) rp[4096] = part[255];
}

// scatter packed (col,val) pairs into CSR order
__global__ void scatter2_kernel(const int* __restrict__ r1, const int* __restrict__ c1, const float* __restrict__ v1,
                                const int* __restrict__ r2, const int* __restrict__ c2, const float* __restrict__ v2,
                                int* __restrict__ cur1, int* __restrict__ cur2,
                                int2* __restrict__ ep1, int2* __restrict__ ep2) {
    int e = blockIdx.x * blockDim.x + threadIdx.x;
    if (e < NNZE) {
        int pos = atomicAdd(&cur1[r1[e]], 1);
        ep1[pos] = make_int2(c1[e], __float_as_int(v1[e]));
    } else {
        int ee = e - NNZE;
        int pos = atomicAdd(&cur2[r2[ee]], 1);
        ep2[pos] = make_int2(c2[ee], __float_as_int(v2[ee]));
    }
}

// ---------- transpose y -> x0 row layout [n][b*16+f], bf16 (no LDS) ----------
__global__ void transA_kernel(const float* __restrict__ y, unsigned short* __restrict__ x0h) {
    int t = threadIdx.x, n = blockIdx.x;   // 128 threads
    int b = t & 31, q = t >> 5;
    float4 y4 = *(const float4*)(y + (size_t)b * (NN * 16) + n * 16 + 4 * q);
    uint2 o;
    o.x = f2bf(y4.x) | (f2bf(y4.y) << 16);
    o.y = f2bf(y4.z) | (f2bf(y4.w) << 16);
    *(uint2*)(x0h + (size_t)n * WA + b * 16 + 4 * q) = o;
}

// ---------- spmmD: 512-wide bf16 spmm, readlane edge broadcast, no LDS ----------
struct SpmmDesc {
    const unsigned short* in;     // [NN][512] bf16
    const unsigned short* prev;   // nullptr if beta==0
    float* outF;                  // exactly one of outF/outH non-null
    unsigned short* outH;
    const int* rp; const int2* ep;
    float alpha, beta;
};

__device__ __forceinline__ void gather_row(const unsigned short* __restrict__ in,
                                           const int* __restrict__ rp, const int2* __restrict__ ep,
                                           int row, int t, float* acc) {
    int beg = rp[row], end = rp[row + 1];
    for (int i0 = beg; i0 < end; i0 += 64) {
        int nn = end - i0; if (nn > 64) nn = 64;
        int2 epr = make_int2(0, 0);
        if (i0 + t < end) epr = ep[i0 + t];
        int vcol = epr.x, vvb = epr.y;
#pragma unroll 4
        for (int j = 0; j < nn; ++j) {
            int sc = __builtin_amdgcn_readlane(vcol, j);          // SGPR col -> scalar base
            float v = __int_as_float(__builtin_amdgcn_readlane(vvb, j));
            const uint4* xr = (const uint4*)(in + (size_t)sc * WD);
            uint4 xv = xr[t];
            acc[0] += v * bf2f_lo(xv.x); acc[1] += v * bf2f_hi(xv.x);
            acc[2] += v * bf2f_lo(xv.y); acc[3] += v * bf2f_hi(xv.y);
            acc[4] += v * bf2f_lo(xv.z); acc[5] += v * bf2f_hi(xv.z);
            acc[6] += v * bf2f_lo(xv.w); acc[7] += v * bf2f_hi(xv.w);
        }
    }
}

__launch_bounds__(64)
__global__ void spmmD_kernel(SpmmDesc q0, SpmmDesc q1, SpmmDesc q2, SpmmDesc q3, int ninst) {
    int blk = blockIdx.x;
    int xcd = blk & 7;
    int idx = blk >> 3;
    int spx = 8 / ninst;                 // XCD slots per instance
    int inst = xcd / spx;                // each instance's 4MB source stays L2-resident per XCD
    int sub  = xcd - inst * spx;
    int row  = sub * (NN / spx) + idx;   // bijective over (inst,row)
    SpmmDesc q = (inst == 0) ? q0 : (inst == 1) ? q1 : (inst == 2) ? q2 : q3;
    int t = threadIdx.x;   // 64 threads, uint4 (8 bf16) each
    float acc[8];
#pragma unroll
    for (int k = 0; k < 8; ++k) acc[k] = 0.f;
    gather_row(q.in, q.rp, q.ep, row, t, acc);
    float r[8];
#pragma unroll
    for (int k = 0; k < 8; ++k) r[k] = q.alpha * acc[k];
    if (q.prev) {
        uint4 pv = ((const uint4*)(q.prev + (size_t)row * WD))[t];
        r[0] += q.beta * bf2f_lo(pv.x); r[1] += q.beta * bf2f_hi(pv.x);
        r[2] += q.beta * bf2f_lo(pv.y); r[3] += q.beta * bf2f_hi(pv.y);
        r[4] += q.beta * bf2f_lo(pv.z); r[5] += q.beta * bf2f_hi(pv.z);
        r[6] += q.beta * bf2f_lo(pv.w); r[7] += q.beta * bf2f_hi(pv.w);
    }
    if (q.outF) {
        float* po = q.outF + (size_t)row * WD + t * 8;
        *(float4*)(po)     = make_float4(r[0], r[1], r[2], r[3]);
        *(float4*)(po + 4) = make_float4(r[4], r[5], r[6], r[7]);
    } else {
        uint4 o;
        o.x = f2bf(r[0]) | (f2bf(r[1]) << 16);
        o.y = f2bf(r[2]) | (f2bf(r[3]) << 16);
        o.z = f2bf(r[4]) | (f2bf(r[5]) << 16);
        o.w = f2bf(r[6]) | (f2bf(r[7]) << 16);
        ((uint4*)(q.outH + (size_t)row * WD))[t] = o;
    }
}

// ---------- projA via MFMA: [32 b][80 k(m*16+f)] @ W[80][80] per n ----------
// k-slot convention: k = kt*32 + g*8 + j (g=lane>>4, j=elem). Same map used for
// A (contiguous 16B global load) and B (LDS-staged W^T) -> permutation-safe.
// D layout (verified): col = lane&15, row = g*4 + reg.
__launch_bounds__(256)
__global__ void projA_mfma(const unsigned short* __restrict__ xh,   // [5][NN][b*16+f] bf16
                           const float* __restrict__ Wtheta, const float* __restrict__ Whid,
                           const float* __restrict__ b_hid,
                           float* __restrict__ theta,               // [NN][b*16+u']
                           unsigned short* __restrict__ c) {        // [NN][b*64+u] bf16
    __shared__ __align__(16) unsigned short sW[80 * 104];   // [col][k], pad 104 (16.6 KB)
    int t = threadIdx.x;
    // stage W bf16 as [col][k=m*16+f]; k in [80,96) zero (K padded to 96)
    for (int i = t; i < 80 * 96; i += 256) {
        int col = i / 96, k = i - col * 96;
        int m = k >> 4, f = k & 15;
        float v = 0.f;
        if (m < 5) v = (col < 16) ? Wtheta[(f * 5 + m) * 16 + col]
                                  : Whid[(f * 5 + m) * 64 + (col - 16)];
        sW[col * 104 + k] = (unsigned short)f2bf(v);
    }
    __syncthreads();
    int lane = t & 63, w = t >> 6;
    int r = lane & 15, g = lane >> 4;
    bf16x8 wf[5][3];
#pragma unroll
    for (int ct = 0; ct < 5; ++ct)
#pragma unroll
        for (int kt = 0; kt < 3; ++kt)
            wf[ct][kt] = *(const bf16x8*)(sW + (ct * 16 + r) * 104 + kt * 32 + g * 8);
    float bh[4];
#pragma unroll
    for (int ct = 0; ct < 4; ++ct) bh[ct] = b_hid[ct * 16 + r];

    for (int i = 0; i < 2; ++i) {
        int n = blockIdx.x * 8 + w * 2 + i;
        f32x4 acc[2][5];
#pragma unroll
        for (int bt = 0; bt < 2; ++bt)
#pragma unroll
            for (int ct = 0; ct < 5; ++ct)
                acc[bt][ct] = (f32x4){0.f, 0.f, 0.f, 0.f};
#pragma unroll
        for (int kt = 0; kt < 3; ++kt) {
            bf16x8 a[2];
            int m = kt * 2 + (g >> 1);
#pragma unroll
            for (int bt = 0; bt < 2; ++bt) {
                bf16x8 av = {0, 0, 0, 0, 0, 0, 0, 0};
                if (m < 5)
                    av = *(const bf16x8*)(xh + ((size_t)m * NN + n) * WA
                                          + (bt * 16 + r) * 16 + (g & 1) * 8);
                a[bt] = av;
            }
#pragma unroll
            for (int bt = 0; bt < 2; ++bt)
#pragma unroll
                for (int ct = 0; ct < 5; ++ct)
                    acc[bt][ct] = __builtin_amdgcn_mfma_f32_16x16x32_bf16(
                        a[bt], wf[ct][kt], acc[bt][ct], 0, 0, 0);
        }
#pragma unroll
        for (int bt = 0; bt < 2; ++bt) {
#pragma unroll
            for (int reg = 0; reg < 4; ++reg) {
                int b = bt * 16 + g * 4 + reg;
                theta[(size_t)n * 512 + b * 16 + r] = acc[bt][0][reg];
            }
#pragma unroll
            for (int ct = 1; ct < 5; ++ct) {
                int u = (ct - 1) * 16 + r;
#pragma unroll
                for (int reg = 0; reg < 4; ++reg) {
                    int b = bt * 16 + g * 4 + reg;
                    float hv = tanhf(acc[bt][ct][reg] + bh[ct - 1]);
                    c[(size_t)n * WB + b * 64 + u] = (unsigned short)f2bf(hv);
                }
            }
        }
    }
}

// ---------- preproj via MFMA: [32 b][64 u] @ Wout[64][80 (m*16+u')] per n ----------
__launch_bounds__(256)
__global__ void preproj_mfma(const unsigned short* __restrict__ c,  // [NN][b*64+u] bf16
                             const float* __restrict__ Wout,        // [(u*5+m)*16+u']
                             float* __restrict__ d0,
                             unsigned short* __restrict__ dd1, unsigned short* __restrict__ dd2,
                             unsigned short* __restrict__ dd3, unsigned short* __restrict__ dd4) {
    __shared__ __align__(16) unsigned short sW[80 * 72];    // [col=m*16+u'][k=u] (11.3 KB)
    int t = threadIdx.x;
    for (int i = t; i < 80 * 64; i += 256) {
        int col = i >> 6, k = i & 63;
        int m = col >> 4, up = col & 15;
        sW[col * 72 + k] = (unsigned short)f2bf(Wout[(k * 5 + m) * 16 + up]);
    }
    __syncthreads();
    int lane = t & 63, w = t >> 6;
    int r = lane & 15, g = lane >> 4;
    bf16x8 wf[5][2];
#pragma unroll
    for (int ct = 0; ct < 5; ++ct)
#pragma unroll
        for (int kt = 0; kt < 2; ++kt)
            wf[ct][kt] = *(const bf16x8*)(sW + (ct * 16 + r) * 72 + kt * 32 + g * 8);

    for (int i = 0; i < 2; ++i) {
        int n = blockIdx.x * 8 + w * 2 + i;
        f32x4 acc[2][5];
#pragma unroll
        for (int bt = 0; bt < 2; ++bt)
#pragma unroll
            for (int ct = 0; ct < 5; ++ct)
                acc[bt][ct] = (f32x4){0.f, 0.f, 0.f, 0.f};
#pragma unroll
        for (int kt = 0; kt < 2; ++kt) {
            bf16x8 a[2];
#pragma unroll
            for (int bt = 0; bt < 2; ++bt)
                a[bt] = *(const bf16x8*)(c + (size_t)n * WB + (bt * 16 + r) * 64
                                         + kt * 32 + g * 8);
#pragma unroll
            for (int bt = 0; bt < 2; ++bt)
#pragma unroll
                for (int ct = 0; ct < 5; ++ct)
                    acc[bt][ct] = __builtin_amdgcn_mfma_f32_16x16x32_bf16(
                        a[bt], wf[ct][kt], acc[bt][ct], 0, 0, 0);
        }
#pragma unroll
        for (int bt = 0; bt < 2; ++bt) {
#pragma unroll
            for (int reg = 0; reg < 4; ++reg) {
                int b = bt * 16 + g * 4 + reg;
                d0[(size_t)n * WD + b * 16 + r] = acc[bt][0][reg];
            }
#pragma unroll
            for (int ct = 1; ct < 5; ++ct) {
                unsigned short* dp = (ct == 1) ? dd1 : (ct == 2) ? dd2 : (ct == 3) ? dd3 : dd4;
#pragma unroll
                for (int reg = 0; reg < 4; ++reg) {
                    int b = bt * 16 + g * 4 + reg;
                    dp[(size_t)n * WD + b * 16 + r] = (unsigned short)f2bf(acc[bt][ct][reg]);
                }
            }
        }
    }
}

// ---------- fused B2+final: per row, gather S1@g1 and S2@g3, then combine ----------
// out = -sigmoid(theta+bl) * tanh(d0 - d2 - d4 + S1@g1 + S2@g3 + bl)
__launch_bounds__(64)
__global__ void finalspmm_kernel(const unsigned short* __restrict__ g1, const unsigned short* __restrict__ g3,
                                 const int* __restrict__ rp1, const int2* __restrict__ ep1,
                                 const int* __restrict__ rp2, const int2* __restrict__ ep2,
                                 const float* __restrict__ theta, const float* __restrict__ d0,
                                 const unsigned short* __restrict__ dd2, const unsigned short* __restrict__ dd4,
                                 const float* __restrict__ b_lat, float* __restrict__ out) {
    int blk = blockIdx.x;
    int row = (blk & 7) * 512 + (blk >> 3);   // XCD-chunked, bijective
    int t = threadIdx.x;                      // 64 threads, 8 elems each
    float h[8];
#pragma unroll
    for (int k = 0; k < 8; ++k) h[k] = 0.f;
    gather_row(g1, rp1, ep1, row, t, h);
    gather_row(g3, rp2, ep2, row, t, h);
    // combine: i = t*8 + j ; b = i>>4 = t>>1 ; u = (t&1)*8 + j
    size_t base = (size_t)row * WD + t * 8;
    float4 dA = *(const float4*)(d0 + base);
    float4 dB = *(const float4*)(d0 + base + 4);
    uint4 p2 = *(const uint4*)(dd2 + base);
    uint4 p4 = *(const uint4*)(dd4 + base);
    float4 tA = *(const float4*)(theta + base);
    float4 tB = *(const float4*)(theta + base + 4);
    float4 blA = *(const float4*)(b_lat + (t & 1) * 8);
    float4 blB = *(const float4*)(b_lat + (t & 1) * 8 + 4);
    float tot[8], th[8];
    tot[0] = dA.x - bf2f_lo(p2.x) - bf2f_lo(p4.x) + h[0] + blA.x;
    tot[1] = dA.y - bf2f_hi(p2.x) - bf2f_hi(p4.x) + h[1] + blA.y;
    tot[2] = dA.z - bf2f_lo(p2.y) - bf2f_lo(p4.y) + h[2] + blA.z;
    tot[3] = dA.w - bf2f_hi(p2.y) - bf2f_hi(p4.y) + h[3] + blA.w;
    tot[4] = dB.x - bf2f_lo(p2.z) - bf2f_lo(p4.z) + h[4] + blB.x;
    tot[5] = dB.y - bf2f_hi(p2.z) - bf2f_hi(p4.z) + h[5] + blB.y;
    tot[6] = dB.z - bf2f_lo(p2.w) - bf2f_lo(p4.w) + h[6] + blB.z;
    tot[7] = dB.w - bf2f_hi(p2.w) - bf2f_hi(p4.w) + h[7] + blB.w;
    th[0] = tA.x + blA.x; th[1] = tA.y + blA.y; th[2] = tA.z + blA.z; th[3] = tA.w + blA.w;
    th[4] = tB.x + blB.x; th[5] = tB.y + blB.y; th[6] = tB.z + blB.z; th[7] = tB.w + blB.w;
    float res[8];
#pragma unroll
    for (int j = 0; j < 8; ++j)
        res[j] = -(1.f / (1.f + expf(-th[j]))) * tanhf(tot[j]);
    float* po = out + ((size_t)(t >> 1) * NN + row) * 16 + (t & 1) * 8;
    *(float4*)(po)     = make_float4(res[0], res[1], res[2], res[3]);
    *(float4*)(po + 4) = make_float4(res[4], res[5], res[6], res[7]);
}

extern "C" void kernel_launch(void* const* d_in, const int* in_sizes, int n_in,
                              void* d_out, int out_size, void* d_ws, size_t ws_size,
                              hipStream_t stream) {
    const float* y      = (const float*)d_in[1];
    const float* Wtheta = (const float*)d_in[2];
    const float* b_lat  = (const float*)d_in[3];
    const float* Whid   = (const float*)d_in[4];
    const float* b_hid  = (const float*)d_in[5];
    const float* Wout   = (const float*)d_in[6];
    const int*   r1     = (const int*)d_in[7];
    const int*   c1     = (const int*)d_in[8];
    const float* v1     = (const float*)d_in[9];
    const int*   r2     = (const int*)d_in[10];
    const int*   c2     = (const int*)d_in[11];
    const float* v2     = (const float*)d_in[12];
    float* out = (float*)d_out;

    // ---- workspace layout ----
    char* ws = (char*)d_ws;
    size_t off = 0;
    auto alloc = [&](size_t bytes) -> char* {
        char* p = ws + off;
        off += (bytes + 255) & ~(size_t)255;
        return p;
    };
    int*   rp1   = (int*)alloc(4097 * 4);
    int*   rp2   = (int*)alloc(4097 * 4);
    int*   cur1  = (int*)alloc(4096 * 4);            // cur1+cur2 contiguous (single memset)
    int*   cur2  = (int*)alloc(4096 * 4);
    int2*  ep1   = (int2*)alloc((size_t)NNZE * 8);
    int2*  ep2   = (int2*)alloc((size_t)NNZE * 8);
    unsigned short* xh = (unsigned short*)alloc((size_t)5 * NN * WA * 2); // 20 MB bf16 [m][n][512]
    float* theta = (float*)alloc((size_t)NN * 512 * 4);                   //  8 MB
    char*  creg  = alloc((size_t)NN * WB * 2);                            // 16 MB (c bf16)
    float* d0 = (float*)alloc((size_t)NN * WD * 4);                       //  8 MB
    unsigned short* g1 = (unsigned short*)alloc((size_t)NN * WD * 2);     //  4 MB
    unsigned short* g3 = (unsigned short*)alloc((size_t)NN * WD * 2);     //  4 MB
    if (off > ws_size) return;   // fail loudly if ws too small

    unsigned short* x0h = xh;
    unsigned short* x1h = xh + (size_t)1 * NN * WA;
    unsigned short* x2h = xh + (size_t)2 * NN * WA;
    unsigned short* x3h = xh + (size_t)3 * NN * WA;
    unsigned short* x4h = xh + (size_t)4 * NN * WA;
    unsigned short* cbuf = (unsigned short*)creg;
    // xh dead after projA -> overlay dd1..dd4 (16 MB of 20)
    unsigned short* dd1 = (unsigned short*)((char*)xh + ((size_t)0  << 20));
    unsigned short* dd2 = (unsigned short*)((char*)xh + ((size_t)4  << 20));
    unsigned short* dd3 = (unsigned short*)((char*)xh + ((size_t)8  << 20));
    unsigned short* dd4 = (unsigned short*)((char*)xh + ((size_t)12 << 20));

    // ---- CSR build ----
    hipMemsetAsync(cur1, 0, 2 * 4096 * 4, stream);
    hist2_kernel<<<2 * NNZE / 256, 256, 0, stream>>>(r1, r2, cur1, cur2);
    scan2_kernel<<<2, 256, 0, stream>>>(cur1, rp1, cur2, rp2);
    scatter2_kernel<<<2 * NNZE / 256, 256, 0, stream>>>(r1, c1, v1, r2, c2, v2,
                                                        cur1, cur2, ep1, ep2);

    // ---- pass A: transpose (bf16, [b*16+f]), 2 narrow spmm launches, MFMA projection ----
    transA_kernel<<<NN, 128, 0, stream>>>(y, x0h);
    {   // x1 = S1@x0, x3 = S2@x0
        SpmmDesc a0 = { x0h, nullptr, nullptr, x1h, rp1, ep1, 1.f, 0.f };
        SpmmDesc a1 = { x0h, nullptr, nullptr, x3h, rp2, ep2, 1.f, 0.f };
        spmmD_kernel<<<2 * NN, 64, 0, stream>>>(a0, a1, a0, a1, 2);
    }
    {   // x2 = 2*S1@x1 - x0, x4 = 2*S2@x3 - x0
        SpmmDesc a0 = { x1h, x0h, nullptr, x2h, rp1, ep1, 2.f, -1.f };
        SpmmDesc a1 = { x3h, x0h, nullptr, x4h, rp2, ep2, 2.f, -1.f };
        spmmD_kernel<<<2 * NN, 64, 0, stream>>>(a0, a1, a0, a1, 2);
    }
    projA_mfma<<<NN / 8, 256, 0, stream>>>(xh, Wtheta, Whid, b_hid, theta, cbuf);

    // ---- pass B (commuted + telescoped): preproj, then TWO spmm rounds total ----
    preproj_mfma<<<NN / 8, 256, 0, stream>>>(cbuf, Wout, d0, dd1, dd2, dd3, dd4);
    {   // g1 = 2*S1@d2 + d1 (bf16), g3 = 2*S2@d4 + d3 (bf16)
        SpmmDesc a0 = { dd2, dd1, nullptr, g1, rp1, ep1, 2.f, 1.f };
        SpmmDesc a1 = { dd4, dd3, nullptr, g3, rp2, ep2, 2.f, 1.f };
        spmmD_kernel<<<2 * NN, 64, 0, stream>>>(a0, a1, a0, a1, 2);
    }
    // fused: out = -sigmoid(theta+bl)*tanh(d0 - d2 - d4 + S1@g1 + S2@g3 + bl)
    finalspmm_kernel<<<NN, 64, 0, stream>>>(g1, g3, rp1, ep1, rp2, ep2,
                                            theta, d0, dd2, dd4, b_lat, out);
}

// Round 9
// 199.380 us; speedup vs baseline: 1.1171x; 1.1171x over previous
//
#include <hip/hip_runtime.h>
#include <stdint.h>

// N=4096, B=32, LATENT=16, UNITS=64, NNZ=65536, K=2, M=5.
#define NN    4096
#define BB    32
#define NNZE  65536
#define WA    512      // pass-A diffusion width (16*B), row layout [b*16+f]
#define WD    512      // pass-B diffusion width (16*B), row layout [b*16+u']

typedef __attribute__((ext_vector_type(8))) short bf16x8;
typedef __attribute__((ext_vector_type(4))) float f32x4;

// ---------- bf16 helpers ----------
__device__ __forceinline__ float bf2f_lo(unsigned int u) {
    union { unsigned int x; float f; } c; c.x = u << 16; return c.f;
}
__device__ __forceinline__ float bf2f_hi(unsigned int u) {
    union { unsigned int x; float f; } c; c.x = u & 0xffff0000u; return c.f;
}
__device__ __forceinline__ float bf2f(unsigned int h) {
    union { unsigned int u; float f; } c; c.u = h << 16; return c.f;
}
__device__ __forceinline__ unsigned int f2bf(float f) {
    union { float ff; unsigned int u; } c; c.ff = f;
    return (c.u + 0x7fffu + ((c.u >> 16) & 1u)) >> 16;
}

// ---------- CSR build (both supports per launch) ----------
__global__ void hist2_kernel(const int* __restrict__ r1, const int* __restrict__ r2,
                             int* __restrict__ cnt1, int* __restrict__ cnt2) {
    int e = blockIdx.x * blockDim.x + threadIdx.x;   // < 2*NNZE
    if (e < NNZE) atomicAdd(&cnt1[r1[e]], 1);
    else          atomicAdd(&cnt2[r2[e - NNZE]], 1);
}

__global__ void scan2_kernel(int* cur1, int* rp1, int* cur2, int* rp2) {
    int* cur = (blockIdx.x == 0) ? cur1 : cur2;
    int* rp  = (blockIdx.x == 0) ? rp1  : rp2;
    __shared__ int part[256];
    int t = threadIdx.x;
    int base = t * 16;
    int loc[16];
    int s = 0;
#pragma unroll
    for (int i = 0; i < 16; ++i) { loc[i] = s; s += cur[base + i]; }
    part[t] = s;
    __syncthreads();
    for (int off = 1; off < 256; off <<= 1) {
        int v = 0;
        if (t >= off) v = part[t - off];
        __syncthreads();
        part[t] += v;
        __syncthreads();
    }
    int excl = (t == 0) ? 0 : part[t - 1];
#pragma unroll
    for (int i = 0; i < 16; ++i) rp[base + i] = excl + loc[i];
    __syncthreads();
#pragma unroll
    for (int i = 0; i < 16; ++i) cur[base + i] = rp[base + i];
    if (t == 255) rp[4096] = part[255];
}

// scatter packed (col,val) pairs into CSR order
__global__ void scatter2_kernel(const int* __restrict__ r1, const int* __restrict__ c1, const float* __restrict__ v1,
                                const int* __restrict__ r2, const int* __restrict__ c2, const float* __restrict__ v2,
                                int* __restrict__ cur1, int* __restrict__ cur2,
                                int2* __restrict__ ep1, int2* __restrict__ ep2) {
    int e = blockIdx.x * blockDim.x + threadIdx.x;
    if (e < NNZE) {
        int pos = atomicAdd(&cur1[r1[e]], 1);
        ep1[pos] = make_int2(c1[e], __float_as_int(v1[e]));
    } else {
        int ee = e - NNZE;
        int pos = atomicAdd(&cur2[r2[ee]], 1);
        ep2[pos] = make_int2(c2[ee], __float_as_int(v2[ee]));
    }
}

// ---------- transpose y -> x0 row layout [n][b*16+f], bf16 (no LDS) ----------
__global__ void transA_kernel(const float* __restrict__ y, unsigned short* __restrict__ x0h) {
    int t = threadIdx.x, n = blockIdx.x;   // 128 threads
    int b = t & 31, q = t >> 5;
    float4 y4 = *(const float4*)(y + (size_t)b * (NN * 16) + n * 16 + 4 * q);
    uint2 o;
    o.x = f2bf(y4.x) | (f2bf(y4.y) << 16);
    o.y = f2bf(y4.z) | (f2bf(y4.w) << 16);
    *(uint2*)(x0h + (size_t)n * WA + b * 16 + 4 * q) = o;
}

// ---------- spmmD: 512-wide bf16 spmm, LDS-staged edges, multi-instance, XCD-chunked ----------
struct SpmmDesc {
    const unsigned short* in;     // [NN][512] bf16
    const unsigned short* prev;   // nullptr if beta==0
    float* outF;                  // exactly one of outF/outH non-null
    unsigned short* outH;
    const int* rp; const int2* ep;
    float alpha, beta;
};

__device__ __forceinline__ void gather_row_lds(const unsigned short* __restrict__ in,
                                               const int* __restrict__ rp, const int2* __restrict__ ep,
                                               int row, int t, int* scol, float* sval, float* acc) {
    int beg = rp[row], end = rp[row + 1];
    for (int i0 = beg; i0 < end; i0 += 64) {
        int nn = end - i0; if (nn > 64) nn = 64;
        __syncthreads();
        if (t < nn) { int2 e = ep[i0 + t]; scol[t] = e.x; sval[t] = __int_as_float(e.y); }
        __syncthreads();
#pragma unroll 4
        for (int j = 0; j < nn; ++j) {
            const uint4* xr = (const uint4*)(in + (size_t)scol[j] * WD);
            uint4 xv = xr[t];
            float v = sval[j];
            acc[0] += v * bf2f_lo(xv.x); acc[1] += v * bf2f_hi(xv.x);
            acc[2] += v * bf2f_lo(xv.y); acc[3] += v * bf2f_hi(xv.y);
            acc[4] += v * bf2f_lo(xv.z); acc[5] += v * bf2f_hi(xv.z);
            acc[6] += v * bf2f_lo(xv.w); acc[7] += v * bf2f_hi(xv.w);
        }
    }
}

__launch_bounds__(64)
__global__ void spmmD_kernel(SpmmDesc q0, SpmmDesc q1, SpmmDesc q2, SpmmDesc q3, int ninst) {
    __shared__ int scol[64];
    __shared__ float sval[64];
    int blk = blockIdx.x;
    int xcd = blk & 7;
    int idx = blk >> 3;
    int spx = 8 / ninst;                 // XCD slots per instance
    int inst = xcd / spx;                // each instance's 4MB source stays L2-resident per XCD
    int sub  = xcd - inst * spx;
    int row  = sub * (NN / spx) + idx;   // bijective over (inst,row)
    SpmmDesc q = (inst == 0) ? q0 : (inst == 1) ? q1 : (inst == 2) ? q2 : q3;
    int t = threadIdx.x;   // 64 threads, uint4 (8 bf16) each
    float acc[8];
#pragma unroll
    for (int k = 0; k < 8; ++k) acc[k] = 0.f;
    gather_row_lds(q.in, q.rp, q.ep, row, t, scol, sval, acc);
    float r[8];
#pragma unroll
    for (int k = 0; k < 8; ++k) r[k] = q.alpha * acc[k];
    if (q.prev) {
        uint4 pv = ((const uint4*)(q.prev + (size_t)row * WD))[t];
        r[0] += q.beta * bf2f_lo(pv.x); r[1] += q.beta * bf2f_hi(pv.x);
        r[2] += q.beta * bf2f_lo(pv.y); r[3] += q.beta * bf2f_hi(pv.y);
        r[4] += q.beta * bf2f_lo(pv.z); r[5] += q.beta * bf2f_hi(pv.z);
        r[6] += q.beta * bf2f_lo(pv.w); r[7] += q.beta * bf2f_hi(pv.w);
    }
    if (q.outF) {
        float* po = q.outF + (size_t)row * WD + t * 8;
        *(float4*)(po)     = make_float4(r[0], r[1], r[2], r[3]);
        *(float4*)(po + 4) = make_float4(r[4], r[5], r[6], r[7]);
    } else {
        uint4 o;
        o.x = f2bf(r[0]) | (f2bf(r[1]) << 16);
        o.y = f2bf(r[2]) | (f2bf(r[3]) << 16);
        o.z = f2bf(r[4]) | (f2bf(r[5]) << 16);
        o.w = f2bf(r[6]) | (f2bf(r[7]) << 16);
        ((uint4*)(q.outH + (size_t)row * WD))[t] = o;
    }
}

// ---------- fused projection: GEMM1 (theta,hid) -> tanh -> LDS transpose -> GEMM2 (Wout) ----------
// k-slot convention (both GEMMs): k = kt*32 + g*8 + j (g=lane>>4, j=elem), same map on A and B.
// D layout (verified): col = lane&15 (=r), row = g*4 + reg.
// GEMM1: A = x rows [b=bt*16+r][k=m*16+f] from global; B = [Wtheta|Whid] in sWa.
// c transpose: D-frag (b=g*4+reg, u=(ct-1)*16+r) -> LDS [b][u] -> A-frag (b=bt*16+r, k=u).
// Per-wave LDS tile, in-order per-wave LDS pipeline -> no barrier needed.
__launch_bounds__(256)
__global__ void proj_fused(const unsigned short* __restrict__ xh,   // [5][NN][b*16+f] bf16
                           const float* __restrict__ Wtheta, const float* __restrict__ Whid,
                           const float* __restrict__ b_hid, const float* __restrict__ Wout,
                           float* __restrict__ theta,               // [NN][b*16+u']
                           float* __restrict__ d0,
                           unsigned short* __restrict__ dd1, unsigned short* __restrict__ dd2,
                           unsigned short* __restrict__ dd3, unsigned short* __restrict__ dd4) {
    __shared__ __align__(16) unsigned short sWa[80 * 104];   // [col][k=m*16+f], K pad 96->104 (16.6 KB)
    __shared__ __align__(16) unsigned short sWo[80 * 72];    // [col=m*16+u'][k=u] (11.3 KB)
    __shared__ __align__(16) unsigned short sC[4][32 * 72];  // per-wave tanh(c) tile (18.4 KB)
    int t = threadIdx.x;
    for (int i = t; i < 80 * 96; i += 256) {
        int col = i / 96, k = i - col * 96;
        int m = k >> 4, f = k & 15;
        float v = 0.f;
        if (m < 5) v = (col < 16) ? Wtheta[(f * 5 + m) * 16 + col]
                                  : Whid[(f * 5 + m) * 64 + (col - 16)];
        sWa[col * 104 + k] = (unsigned short)f2bf(v);
    }
    for (int i = t; i < 80 * 64; i += 256) {
        int col = i >> 6, k = i & 63;
        int m = col >> 4, up = col & 15;
        sWo[col * 72 + k] = (unsigned short)f2bf(Wout[(k * 5 + m) * 16 + up]);
    }
    __syncthreads();
    int lane = t & 63, w = t >> 6;
    int r = lane & 15, g = lane >> 4;
    bf16x8 wfa[5][3];
#pragma unroll
    for (int ct = 0; ct < 5; ++ct)
#pragma unroll
        for (int kt = 0; kt < 3; ++kt)
            wfa[ct][kt] = *(const bf16x8*)(sWa + (ct * 16 + r) * 104 + kt * 32 + g * 8);
    float bh[4];
#pragma unroll
    for (int ct = 0; ct < 4; ++ct) bh[ct] = b_hid[ct * 16 + r];
    unsigned short* myC = (unsigned short*)sC[w];

    for (int i = 0; i < 2; ++i) {
        int n = blockIdx.x * 8 + w * 2 + i;
        // ---- GEMM1: [32 b][96 k] @ [96][80] ----
        f32x4 acc[2][5];
#pragma unroll
        for (int bt = 0; bt < 2; ++bt)
#pragma unroll
            for (int ct = 0; ct < 5; ++ct)
                acc[bt][ct] = (f32x4){0.f, 0.f, 0.f, 0.f};
#pragma unroll
        for (int kt = 0; kt < 3; ++kt) {
            bf16x8 a[2];
            int m = kt * 2 + (g >> 1);
#pragma unroll
            for (int bt = 0; bt < 2; ++bt) {
                bf16x8 av = {0, 0, 0, 0, 0, 0, 0, 0};
                if (m < 5)
                    av = *(const bf16x8*)(xh + ((size_t)m * NN + n) * WA
                                          + (bt * 16 + r) * 16 + (g & 1) * 8);
                a[bt] = av;
            }
#pragma unroll
            for (int bt = 0; bt < 2; ++bt)
#pragma unroll
                for (int ct = 0; ct < 5; ++ct)
                    acc[bt][ct] = __builtin_amdgcn_mfma_f32_16x16x32_bf16(
                        a[bt], wfa[ct][kt], acc[bt][ct], 0, 0, 0);
        }
        // theta store + tanh(c) -> per-wave LDS tile [b][u]
#pragma unroll
        for (int bt = 0; bt < 2; ++bt) {
#pragma unroll
            for (int reg = 0; reg < 4; ++reg) {
                int b = bt * 16 + g * 4 + reg;
                theta[(size_t)n * 512 + b * 16 + r] = acc[bt][0][reg];
            }
#pragma unroll
            for (int ct = 1; ct < 5; ++ct) {
                int u = (ct - 1) * 16 + r;
#pragma unroll
                for (int reg = 0; reg < 4; ++reg) {
                    int b = bt * 16 + g * 4 + reg;
                    myC[b * 72 + u] = (unsigned short)f2bf(tanhf(acc[bt][ct][reg] + bh[ct - 1]));
                }
            }
        }
        // ---- GEMM2: [32 b][64 k=u] @ [64][80 (m*16+u')] ----
        f32x4 acc2[2][5];
#pragma unroll
        for (int bt = 0; bt < 2; ++bt)
#pragma unroll
            for (int ct = 0; ct < 5; ++ct)
                acc2[bt][ct] = (f32x4){0.f, 0.f, 0.f, 0.f};
#pragma unroll
        for (int kt = 0; kt < 2; ++kt) {
            bf16x8 a2[2];
#pragma unroll
            for (int bt = 0; bt < 2; ++bt)
                a2[bt] = *(const bf16x8*)(myC + (bt * 16 + r) * 72 + kt * 32 + g * 8);
#pragma unroll
            for (int ct = 0; ct < 5; ++ct) {
                bf16x8 wo = *(const bf16x8*)(sWo + (ct * 16 + r) * 72 + kt * 32 + g * 8);
#pragma unroll
                for (int bt = 0; bt < 2; ++bt)
                    acc2[bt][ct] = __builtin_amdgcn_mfma_f32_16x16x32_bf16(
                        a2[bt], wo, acc2[bt][ct], 0, 0, 0);
            }
        }
        // d stores
#pragma unroll
        for (int bt = 0; bt < 2; ++bt) {
#pragma unroll
            for (int reg = 0; reg < 4; ++reg) {
                int b = bt * 16 + g * 4 + reg;
                d0[(size_t)n * WD + b * 16 + r] = acc2[bt][0][reg];
            }
#pragma unroll
            for (int ct = 1; ct < 5; ++ct) {
                unsigned short* dp = (ct == 1) ? dd1 : (ct == 2) ? dd2 : (ct == 3) ? dd3 : dd4;
#pragma unroll
                for (int reg = 0; reg < 4; ++reg) {
                    int b = bt * 16 + g * 4 + reg;
                    dp[(size_t)n * WD + b * 16 + r] = (unsigned short)f2bf(acc2[bt][ct][reg]);
                }
            }
        }
    }
}

// ---------- fused B2+final: per row, gather S1@g1 and S2@g3, then combine ----------
// out = -sigmoid(theta+bl) * tanh(d0 - d2 - d4 + S1@g1 + S2@g3 + bl)
__launch_bounds__(64)
__global__ void finalspmm_kernel(const unsigned short* __restrict__ g1, const unsigned short* __restrict__ g3,
                                 const int* __restrict__ rp1, const int2* __restrict__ ep1,
                                 const int* __restrict__ rp2, const int2* __restrict__ ep2,
                                 const float* __restrict__ theta, const float* __restrict__ d0,
                                 const unsigned short* __restrict__ dd2, const unsigned short* __restrict__ dd4,
                                 const float* __restrict__ b_lat, float* __restrict__ out) {
    __shared__ int scol[64];
    __shared__ float sval[64];
    int blk = blockIdx.x;
    int row = (blk & 7) * 512 + (blk >> 3);   // XCD-chunked, bijective
    int t = threadIdx.x;                      // 64 threads, 8 elems each
    float h[8];
#pragma unroll
    for (int k = 0; k < 8; ++k) h[k] = 0.f;
    gather_row_lds(g1, rp1, ep1, row, t, scol, sval, h);
    gather_row_lds(g3, rp2, ep2, row, t, scol, sval, h);
    // combine: i = t*8 + j ; b = i>>4 = t>>1 ; u = (t&1)*8 + j
    size_t base = (size_t)row * WD + t * 8;
    float4 dA = *(const float4*)(d0 + base);
    float4 dB = *(const float4*)(d0 + base + 4);
    uint4 p2 = *(const uint4*)(dd2 + base);
    uint4 p4 = *(const uint4*)(dd4 + base);
    float4 tA = *(const float4*)(theta + base);
    float4 tB = *(const float4*)(theta + base + 4);
    float4 blA = *(const float4*)(b_lat + (t & 1) * 8);
    float4 blB = *(const float4*)(b_lat + (t & 1) * 8 + 4);
    float tot[8], th[8];
    tot[0] = dA.x - bf2f_lo(p2.x) - bf2f_lo(p4.x) + h[0] + blA.x;
    tot[1] = dA.y - bf2f_hi(p2.x) - bf2f_hi(p4.x) + h[1] + blA.y;
    tot[2] = dA.z - bf2f_lo(p2.y) - bf2f_lo(p4.y) + h[2] + blA.z;
    tot[3] = dA.w - bf2f_hi(p2.y) - bf2f_hi(p4.y) + h[3] + blA.w;
    tot[4] = dB.x - bf2f_lo(p2.z) - bf2f_lo(p4.z) + h[4] + blB.x;
    tot[5] = dB.y - bf2f_hi(p2.z) - bf2f_hi(p4.z) + h[5] + blB.y;
    tot[6] = dB.z - bf2f_lo(p2.w) - bf2f_lo(p4.w) + h[6] + blB.z;
    tot[7] = dB.w - bf2f_hi(p2.w) - bf2f_hi(p4.w) + h[7] + blB.w;
    th[0] = tA.x + blA.x; th[1] = tA.y + blA.y; th[2] = tA.z + blA.z; th[3] = tA.w + blA.w;
    th[4] = tB.x + blB.x; th[5] = tB.y + blB.y; th[6] = tB.z + blB.z; th[7] = tB.w + blB.w;
    float res[8];
#pragma unroll
    for (int j = 0; j < 8; ++j)
        res[j] = -(1.f / (1.f + expf(-th[j]))) * tanhf(tot[j]);
    float* po = out + ((size_t)(t >> 1) * NN + row) * 16 + (t & 1) * 8;
    *(float4*)(po)     = make_float4(res[0], res[1], res[2], res[3]);
    *(float4*)(po + 4) = make_float4(res[4], res[5], res[6], res[7]);
}

extern "C" void kernel_launch(void* const* d_in, const int* in_sizes, int n_in,
                              void* d_out, int out_size, void* d_ws, size_t ws_size,
                              hipStream_t stream) {
    const float* y      = (const float*)d_in[1];
    const float* Wtheta = (const float*)d_in[2];
    const float* b_lat  = (const float*)d_in[3];
    const float* Whid   = (const float*)d_in[4];
    const float* b_hid  = (const float*)d_in[5];
    const float* Wout   = (const float*)d_in[6];
    const int*   r1     = (const int*)d_in[7];
    const int*   c1     = (const int*)d_in[8];
    const float* v1     = (const float*)d_in[9];
    const int*   r2     = (const int*)d_in[10];
    const int*   c2     = (const int*)d_in[11];
    const float* v2     = (const float*)d_in[12];
    float* out = (float*)d_out;

    // ---- workspace layout (no overlays — ws is plentiful) ----
    char* ws = (char*)d_ws;
    size_t off = 0;
    auto alloc = [&](size_t bytes) -> char* {
        char* p = ws + off;
        off += (bytes + 255) & ~(size_t)255;
        return p;
    };
    int*   rp1   = (int*)alloc(4097 * 4);
    int*   rp2   = (int*)alloc(4097 * 4);
    int*   cur1  = (int*)alloc(4096 * 4);            // cur1+cur2 contiguous (single memset)
    int*   cur2  = (int*)alloc(4096 * 4);
    int2*  ep1   = (int2*)alloc((size_t)NNZE * 8);
    int2*  ep2   = (int2*)alloc((size_t)NNZE * 8);
    unsigned short* xh = (unsigned short*)alloc((size_t)5 * NN * WA * 2); // 20 MB bf16 [m][n][512]
    float* theta = (float*)alloc((size_t)NN * 512 * 4);                   //  8 MB
    float* d0    = (float*)alloc((size_t)NN * WD * 4);                    //  8 MB
    unsigned short* dd1 = (unsigned short*)alloc((size_t)NN * WD * 2);    //  4 MB
    unsigned short* dd2 = (unsigned short*)alloc((size_t)NN * WD * 2);    //  4 MB
    unsigned short* dd3 = (unsigned short*)alloc((size_t)NN * WD * 2);    //  4 MB
    unsigned short* dd4 = (unsigned short*)alloc((size_t)NN * WD * 2);    //  4 MB
    unsigned short* g1  = (unsigned short*)alloc((size_t)NN * WD * 2);    //  4 MB
    unsigned short* g3  = (unsigned short*)alloc((size_t)NN * WD * 2);    //  4 MB
    if (off > ws_size) return;   // fail loudly if ws too small

    unsigned short* x0h = xh;
    unsigned short* x1h = xh + (size_t)1 * NN * WA;
    unsigned short* x2h = xh + (size_t)2 * NN * WA;
    unsigned short* x3h = xh + (size_t)3 * NN * WA;
    unsigned short* x4h = xh + (size_t)4 * NN * WA;

    // ---- CSR build ----
    hipMemsetAsync(cur1, 0, 2 * 4096 * 4, stream);
    hist2_kernel<<<2 * NNZE / 256, 256, 0, stream>>>(r1, r2, cur1, cur2);
    scan2_kernel<<<2, 256, 0, stream>>>(cur1, rp1, cur2, rp2);
    scatter2_kernel<<<2 * NNZE / 256, 256, 0, stream>>>(r1, c1, v1, r2, c2, v2,
                                                        cur1, cur2, ep1, ep2);

    // ---- pass A: transpose (bf16, [b*16+f]), 2 narrow spmm launches ----
    transA_kernel<<<NN, 128, 0, stream>>>(y, x0h);
    {   // x1 = S1@x0, x3 = S2@x0
        SpmmDesc a0 = { x0h, nullptr, nullptr, x1h, rp1, ep1, 1.f, 0.f };
        SpmmDesc a1 = { x0h, nullptr, nullptr, x3h, rp2, ep2, 1.f, 0.f };
        spmmD_kernel<<<2 * NN, 64, 0, stream>>>(a0, a1, a0, a1, 2);
    }
    {   // x2 = 2*S1@x1 - x0, x4 = 2*S2@x3 - x0
        SpmmDesc a0 = { x1h, x0h, nullptr, x2h, rp1, ep1, 2.f, -1.f };
        SpmmDesc a1 = { x3h, x0h, nullptr, x4h, rp2, ep2, 2.f, -1.f };
        spmmD_kernel<<<2 * NN, 64, 0, stream>>>(a0, a1, a0, a1, 2);
    }

    // ---- fused projection: theta + tanh(hid) -> d0..d4 in one kernel ----
    proj_fused<<<NN / 8, 256, 0, stream>>>(xh, Wtheta, Whid, b_hid, Wout,
                                           theta, d0, dd1, dd2, dd3, dd4);

    // ---- pass B (commuted + telescoped): one spmm round, then fused final ----
    {   // g1 = 2*S1@d2 + d1 (bf16), g3 = 2*S2@d4 + d3 (bf16)
        SpmmDesc a0 = { dd2, dd1, nullptr, g1, rp1, ep1, 2.f, 1.f };
        SpmmDesc a1 = { dd4, dd3, nullptr, g3, rp2, ep2, 2.f, 1.f };
        spmmD_kernel<<<2 * NN, 64, 0, stream>>>(a0, a1, a0, a1, 2);
    }
    // fused: out = -sigmoid(theta+bl)*tanh(d0 - d2 - d4 + S1@g1 + S2@g3 + bl)
    finalspmm_kernel<<<NN, 64, 0, stream>>>(g1, g3, rp1, ep1, rp2, ep2,
                                            theta, d0, dd2, dd4, b_lat, out);
}